// Round 1
// baseline (181.413 us; speedup 1.0000x reference)
//
#include <hip/hip_runtime.h>

// Problem dims (fixed by reference): B=1, H=W=128, C=1280
// HW = 16384 pixels, 19 "relation" channels, 1024 softmax keys.
//
// ws layout (floats):
//   m1  : [19][1280]              off 0       len 24320   (v2@v1)
//   m2  : [1280][20] (pad 19->20) off 24320   len 25600   (w2@w1, row-padded)
//   imt : [1024][20] (pad 19->20) off 49920   len 20480   (intra[i] transposed)
//   xm  : [19][16384]             off 70400   len 311296  (x_m, o-major = flat view)
//   cab : [16384][19]             off 381696  len 311296  (n-major = flat view)
// total 692992 floats = 2.77 MB

#define OFF_M2  24320
#define OFF_IMT 49920
#define OFF_XM  70400
#define OFF_CAB 381696

__global__ __launch_bounds__(256) void prep_kernel(
    const float* __restrict__ v1, const float* __restrict__ v2,
    const float* __restrict__ w1, const float* __restrict__ w2,
    const float* __restrict__ intra, const int* __restrict__ ip,
    float* __restrict__ ws)
{
  float* m1  = ws;
  float* m2  = ws + OFF_M2;
  float* imt = ws + OFF_IMT;
  const int blk = blockIdx.x;
  const int tid = threadIdx.x;
  if (blk < 95) {
    // M1[o][j] = sum_c v2[o][c] * v1[c][j]   (19 x 1280)
    int t = blk * 256 + tid;           // 1280 = 5*256 -> o uniform per block
    int o = t / 1280, j = t % 1280;
    float acc = 0.f;
#pragma unroll 4
    for (int c = 0; c < 512; ++c)
      acc = fmaf(v2[o * 512 + c], v1[c * 1280 + j], acc);
    m1[t] = acc;
  } else if (blk < 190) {
    // M2[o][d] = sum_c w2[o][c] * w1[c][d]   (1280 x 19, stored padded to 20)
    int t = (blk - 95) * 256 + tid;
    int o = t / 19, d = t % 19;
    float acc = 0.f;
#pragma unroll 4
    for (int c = 0; c < 512; ++c)
      acc = fmaf(w2[o * 512 + c], w1[c * 19 + d], acc);
    m2[o * 20 + d] = acc;
    if (d == 0) m2[o * 20 + 19] = 0.f;
  } else {
    // imt[k][c] = intra[i][c][k]  (transpose for wave-uniform scalar loads in K3)
    int t = (blk - 190) * 256 + tid;   // 19456 = 76*256
    int c = t / 1024, k = t % 1024;
    int iv = *ip;
    imt[k * 20 + c] = intra[(size_t)iv * 19456 + c * 1024 + k];
    if (c == 0) imt[k * 20 + 19] = 0.f;
  }
}

// K2: xm[o][hw] = sum_c M1[o][c] * x[hw+128 row][c]; blocks 256.. copy cls row.
__global__ __launch_bounds__(512) void xm_kernel(
    const float* __restrict__ x, const float* __restrict__ m1,
    float* __restrict__ xm, float* __restrict__ out)
{
  __shared__ float red[8][64][19];
  const int blk = blockIdx.x;
  const int tid = threadIdx.x;
  if (blk < 256) {
    const int p  = tid & 63;                 // pixel within block
    const int kp = tid >> 6;                 // k-part (c-range), uniform per wave
    const int kpu = __builtin_amdgcn_readfirstlane(kp);
    const int n = blk * 64 + p;
    const float* xrow = x + (size_t)(n + 128) * 1280;
    float acc[19];
#pragma unroll
    for (int o = 0; o < 19; ++o) acc[o] = 0.f;
    const int cbase = kpu * 160;
    for (int jj = 0; jj < 40; ++jj) {
      const int c = cbase + jj * 4;
      const float4 xv = *reinterpret_cast<const float4*>(xrow + c);
#pragma unroll
      for (int o = 0; o < 19; ++o) {
        const float4 m = *reinterpret_cast<const float4*>(m1 + o * 1280 + c);
        acc[o] = fmaf(m.x, xv.x, fmaf(m.y, xv.y, fmaf(m.z, xv.z, fmaf(m.w, xv.w, acc[o]))));
      }
    }
#pragma unroll
    for (int o = 0; o < 19; ++o) red[kp][p][o] = acc[o];
    __syncthreads();
    for (int idx = tid; idx < 64 * 19; idx += 512) {
      int pp = idx / 19, o = idx % 19;
      float s = 0.f;
#pragma unroll
      for (int q = 0; q < 8; ++q) s += red[q][pp][o];
      xm[o * 16384 + blk * 64 + pp] = s;
    }
  } else {
    // cls row: out[0][w][c] = x[0][w][c]  (163840 floats = 40960 float4)
    const float4* xf = reinterpret_cast<const float4*>(x);
    float4* of = reinterpret_cast<float4*>(out);
    for (int idx = (blk - 256) * 512 + tid; idx < 40960; idx += 8 * 512)
      of[idx] = xf[idx];
  }
}

// K3: per row n (16384): s_k = xv . imt[k]; p=exp(s); Z+=p; out_c += p*imt[k][c];
// then outn = out/Z; cab[n][d] = sum_c outn[c] * inter[i][c][d].
// No max-subtraction needed: |s| = O(1), exp cannot overflow -> partials add.
__global__ __launch_bounds__(512) void soft_kernel(
    const float* __restrict__ xm, const float* __restrict__ imt,
    const float* __restrict__ inter, const int* __restrict__ ip,
    float* __restrict__ cab)
{
  __shared__ float red[8][64][20];
  __shared__ float outn[64 * 19];
  __shared__ float il[361];
  const int blk = blockIdx.x, tid = threadIdx.x;
  const int r = tid & 63, kp = tid >> 6;
  const int kpu = __builtin_amdgcn_readfirstlane(kp);
  const int n = blk * 64 + r;

  if (tid < 361) {
    int iv = *ip;
    il[tid] = inter[(size_t)iv * 361 + tid];
  }

  const float* xrow = xm + (size_t)n * 19;
  float xv[19];
#pragma unroll
  for (int c = 0; c < 19; ++c) xv[c] = xrow[c];
  float outp[19];
#pragma unroll
  for (int c = 0; c < 19; ++c) outp[c] = 0.f;
  float Z = 0.f;
  const int kbase = kpu * 128;
  for (int k = kbase; k < kbase + 128; ++k) {
    const float* w = imt + k * 20;       // wave-uniform -> scalar loads
    // 4-way split dot to shorten the dependence chain
    float s0 = 0.f, s1 = 0.f, s2 = 0.f, s3 = 0.f;
#pragma unroll
    for (int c = 0; c < 16; c += 4) {
      s0 = fmaf(xv[c + 0], w[c + 0], s0);
      s1 = fmaf(xv[c + 1], w[c + 1], s1);
      s2 = fmaf(xv[c + 2], w[c + 2], s2);
      s3 = fmaf(xv[c + 3], w[c + 3], s3);
    }
    s0 = fmaf(xv[16], w[16], s0);
    s1 = fmaf(xv[17], w[17], s1);
    s2 = fmaf(xv[18], w[18], s2);
    float s = (s0 + s1) + (s2 + s3);
    float pv = __expf(s);
    Z += pv;
#pragma unroll
    for (int c = 0; c < 19; ++c) outp[c] = fmaf(pv, w[c], outp[c]);
  }
#pragma unroll
  for (int c = 0; c < 19; ++c) red[kp][r][c] = outp[c];
  red[kp][r][19] = Z;
  __syncthreads();
  for (int idx = tid; idx < 64 * 19; idx += 512) {
    int rr = idx / 19, c = idx % 19;
    float s = 0.f, Zs = 0.f;
#pragma unroll
    for (int q = 0; q < 8; ++q) { s += red[q][rr][c]; Zs += red[q][rr][19]; }
    outn[idx] = s / Zs;
  }
  __syncthreads();
  for (int idx = tid; idx < 64 * 19; idx += 512) {
    int rr = idx / 19, d = idx % 19;
    float acc = 0.f;
#pragma unroll
    for (int c = 0; c < 19; ++c) acc = fmaf(outn[rr * 19 + c], il[c * 19 + d], acc);
    cab[(size_t)blk * 64 * 19 + idx] = acc;   // (n0+rr)*19+d == blk*1216+idx
  }
}

// K4: out[hh][w][c] = relu(sum_d M2[c][d]*cab4[d][hw]) + x[hh][w][c], hh=hw/128+1
// cab4[d][hw] = cab_flat[d*16384+hw] (reshape reinterpretation).
__global__ __launch_bounds__(256) void out_kernel(
    const float* __restrict__ x, const float* __restrict__ ws,
    float* __restrict__ out)
{
  const float* m2  = ws + OFF_M2;
  const float* cab = ws + OFF_CAB;
  __shared__ float cv[19][32];
  const int blk = blockIdx.x, tid = threadIdx.x;
  const int hw0 = blk * 32;
  for (int idx = tid; idx < 19 * 32; idx += 256) {
    int dd = idx >> 5, p = idx & 31;
    cv[dd][p] = cab[(size_t)dd * 16384 + hw0 + p];
  }
  __syncthreads();
  // Own 5 channels (c = tid + 256*ci), keep all 19 M2 coeffs per channel in regs.
  float4 m2r[5][5];
#pragma unroll
  for (int ci = 0; ci < 5; ++ci) {
    const int c = tid + 256 * ci;
    const float4* mrow = reinterpret_cast<const float4*>(m2 + c * 20);
#pragma unroll
    for (int q = 0; q < 5; ++q) m2r[ci][q] = mrow[q];
  }
  for (int g = 0; g < 8; ++g) {
    const int p0 = g * 4;
    float4 acc[5];
#pragma unroll
    for (int ci = 0; ci < 5; ++ci) acc[ci] = make_float4(0.f, 0.f, 0.f, 0.f);
#pragma unroll
    for (int k = 0; k < 19; ++k) {
      const float4 c4 = *reinterpret_cast<const float4*>(&cv[k][p0]); // broadcast
#pragma unroll
      for (int ci = 0; ci < 5; ++ci) {
        const float m = reinterpret_cast<const float*>(&m2r[ci][k >> 2])[k & 3];
        acc[ci].x = fmaf(m, c4.x, acc[ci].x);
        acc[ci].y = fmaf(m, c4.y, acc[ci].y);
        acc[ci].z = fmaf(m, c4.z, acc[ci].z);
        acc[ci].w = fmaf(m, c4.w, acc[ci].w);
      }
    }
#pragma unroll
    for (int ci = 0; ci < 5; ++ci) {
      const int c = tid + 256 * ci;
#pragma unroll
      for (int px = 0; px < 4; ++px) {
        const int hw = hw0 + p0 + px;
        const size_t addr = (size_t)(hw + 128) * 1280 + c;
        const float a = (px == 0) ? acc[ci].x : (px == 1) ? acc[ci].y
                       : (px == 2) ? acc[ci].z : acc[ci].w;
        out[addr] = fmaxf(a, 0.f) + x[addr];
      }
    }
  }
}

extern "C" void kernel_launch(void* const* d_in, const int* in_sizes, int n_in,
                              void* d_out, int out_size, void* d_ws, size_t ws_size,
                              hipStream_t stream)
{
  const float* x     = (const float*)d_in[0];
  const float* v1    = (const float*)d_in[1];
  const float* v2    = (const float*)d_in[2];
  const float* w1    = (const float*)d_in[3];
  const float* w2    = (const float*)d_in[4];
  const float* intra = (const float*)d_in[5];
  const float* inter = (const float*)d_in[6];
  const int*   ip    = (const int*)d_in[7];
  float* out = (float*)d_out;
  float* ws  = (float*)d_ws;

  prep_kernel<<<266, 256, 0, stream>>>(v1, v2, w1, w2, intra, ip, ws);
  xm_kernel<<<264, 512, 0, stream>>>(x, ws /*m1*/, ws + OFF_XM, out);
  soft_kernel<<<256, 512, 0, stream>>>(ws + OFF_XM, ws + OFF_IMT, inter, ip, ws + OFF_CAB);
  out_kernel<<<512, 256, 0, stream>>>(x, ws, out);
}

// Round 2
// 161.686 us; speedup vs baseline: 1.1220x; 1.1220x over previous
//
#include <hip/hip_runtime.h>

// B=1, H=W=128, C=1280; HW=16384 pixels, 19 relation channels, 1024 keys.
//
// Algebra: x_m = (v2@v1)·x   (M1: 19x1280)
//          cab = softmax(x_m·imt^T)·im2, im2 = imt@inter  (1024x19)
//          out = relu((w2@w1)·cab) + x  (M2: 1280x19, stored transposed)
//
// ws layout (floats):
//   m1  : [19][1280]             off 0       len 24320
//   m2t : [19][1280]             off 24320   len 24320   (M2 transposed: m2t[d][o])
//   imt : [1024][20] (pad)       off 48640   len 20480   (intra[i]^T)
//   im2 : [1024][20] (pad)       off 69120   len 20480   (imt @ inter[i])
//   xm  : flat 19*16384          off 89600   len 311296  (o-major; reinterpreted n-major)
//   cab : flat 16384*19          off 400896  len 311296  (n-major; reinterpreted d-major)
// total 712192 floats = 2.85 MB

#define OFF_M2T 24320
#define OFF_IMT 48640
#define OFF_IM2 69120
#define OFF_XM  89600
#define OFF_CAB 400896

__global__ __launch_bounds__(256) void prep_kernel(
    const float* __restrict__ v1, const float* __restrict__ v2,
    const float* __restrict__ w1, const float* __restrict__ w2,
    const float* __restrict__ intra, const float* __restrict__ inter,
    const int* __restrict__ ip, float* __restrict__ ws)
{
  float* m1  = ws;
  float* m2t = ws + OFF_M2T;
  float* imt = ws + OFF_IMT;
  float* im2 = ws + OFF_IM2;
  const int blk = blockIdx.x, tid = threadIdx.x;
  if (blk < 380) {
    // M1[o][j] = sum_c v2[o][c]*v1[c][j], 4-way c-split + shfl reduce
    int g = blk * 256 + tid;
    int oidx = g >> 2, part = g & 3;
    int o = oidx / 1280, j = oidx - o * 1280;
    const float* v2r = v2 + o * 512 + part * 128;
    const float* v1c = v1 + part * 128 * 1280 + j;
    float acc = 0.f;
#pragma unroll 8
    for (int c = 0; c < 128; ++c) acc = fmaf(v2r[c], v1c[c * 1280], acc);
    acc += __shfl_xor(acc, 1);
    acc += __shfl_xor(acc, 2);
    if (part == 0) m1[oidx] = acc;
  } else if (blk < 760) {
    // M2t[d][o] = sum_c w2[o][c]*w1[c][d]
    int g = (blk - 380) * 256 + tid;
    int oidx = g >> 2, part = g & 3;
    int o = oidx / 19, d = oidx - o * 19;
    const float* w2r = w2 + o * 512 + part * 128;
    const float* w1c = w1 + part * 128 * 19 + d;
    float acc = 0.f;
#pragma unroll 8
    for (int c = 0; c < 128; ++c) acc = fmaf(w2r[c], w1c[c * 19], acc);
    acc += __shfl_xor(acc, 1);
    acc += __shfl_xor(acc, 2);
    if (part == 0) m2t[d * 1280 + o] = acc;
  } else if (blk < 836) {
    // imt[k][c] = intra[i][c][k]
    int t = (blk - 760) * 256 + tid;
    int c = t >> 10, k = t & 1023;
    int iv = *ip;
    imt[k * 20 + c] = intra[(size_t)iv * 19456 + c * 1024 + k];
    if (c == 0) imt[k * 20 + 19] = 0.f;
  } else {
    // im2[k][d] = sum_c intra[i][c][k]*inter[i][c][d]
    int t = (blk - 836) * 256 + tid;
    int d = t >> 10, k = t & 1023;
    int iv = *ip;
    const float* ib = intra + (size_t)iv * 19456 + k;
    const float* ir = inter + (size_t)iv * 361 + d;
    float acc = 0.f;
#pragma unroll
    for (int c = 0; c < 19; ++c) acc = fmaf(ib[c * 1024], ir[c * 19], acc);
    im2[k * 20 + d] = acc;
    if (d == 0) im2[k * 20 + 19] = 0.f;
  }
}

// K2: xm[o][hw] = sum_c M1[o][c]*x[hw+128][c]. 1024 thr: 64 px x 16 c-parts.
__global__ __launch_bounds__(1024) void xm_kernel(
    const float* __restrict__ x, const float* __restrict__ m1,
    float* __restrict__ xm, float* __restrict__ out)
{
  __shared__ float red[16][64][19];
  const int blk = blockIdx.x, tid = threadIdx.x;
  if (blk < 256) {
    const int p  = tid & 63;
    const int kp = tid >> 6;                        // wave-uniform
    const int kpu = __builtin_amdgcn_readfirstlane(kp);
    const int n = blk * 64 + p;
    const float* xrow = x + (size_t)(n + 128) * 1280;
    float acc[19];
#pragma unroll
    for (int o = 0; o < 19; ++o) acc[o] = 0.f;
    const int cbase = kpu * 80;
    for (int jj = 0; jj < 20; ++jj) {
      const int c = cbase + jj * 4;
      const float4 xv = *reinterpret_cast<const float4*>(xrow + c);
#pragma unroll
      for (int o = 0; o < 19; ++o) {
        const float4 m = *reinterpret_cast<const float4*>(m1 + o * 1280 + c);
        acc[o] = fmaf(m.x, xv.x, fmaf(m.y, xv.y, fmaf(m.z, xv.z, fmaf(m.w, xv.w, acc[o]))));
      }
    }
#pragma unroll
    for (int o = 0; o < 19; ++o) red[kp][p][o] = acc[o];
    __syncthreads();
    for (int idx = tid; idx < 64 * 19; idx += 1024) {
      int pp = idx / 19, o = idx % 19;
      float s = 0.f;
#pragma unroll
      for (int q = 0; q < 16; ++q) s += red[q][pp][o];
      xm[o * 16384 + blk * 64 + pp] = s;
    }
  } else {
    // cls row copy: out[0][w][c] = x[0][w][c], 40960 float4
    const float4* xf = reinterpret_cast<const float4*>(x);
    float4* of = reinterpret_cast<float4*>(out);
    for (int idx = (blk - 256) * 1024 + tid; idx < 40960; idx += 4 * 1024)
      of[idx] = xf[idx];
  }
}

// K3: per row n: s_k = xv.imt[k]; p=exp(s); Z+=p; outd += p*im2[k];
// cab[n][d] = outd/Z. No max-subtraction: |s|=O(0.1), exp safe, partials add.
__global__ __launch_bounds__(1024) void soft_kernel(
    const float* __restrict__ xm, const float* __restrict__ imt,
    const float* __restrict__ im2, float* __restrict__ cab)
{
  __shared__ float red[16][64][20];
  const int blk = blockIdx.x, tid = threadIdx.x;
  const int r = tid & 63, kp = tid >> 6;
  const int kpu = __builtin_amdgcn_readfirstlane(kp);
  const int n = blk * 64 + r;

  const float* xrow = xm + (size_t)n * 19;
  float xv[19];
#pragma unroll
  for (int c = 0; c < 19; ++c) xv[c] = xrow[c];
  float outp[19];
#pragma unroll
  for (int c = 0; c < 19; ++c) outp[c] = 0.f;
  float Z = 0.f;
  const int kbase = kpu * 64;
  for (int k = kbase; k < kbase + 64; ++k) {
    const float* w = imt + k * 20;       // wave-uniform -> scalar loads
    const float* u = im2 + k * 20;
    float s0 = 0.f, s1 = 0.f, s2 = 0.f, s3 = 0.f;
#pragma unroll
    for (int c = 0; c < 16; c += 4) {
      s0 = fmaf(xv[c + 0], w[c + 0], s0);
      s1 = fmaf(xv[c + 1], w[c + 1], s1);
      s2 = fmaf(xv[c + 2], w[c + 2], s2);
      s3 = fmaf(xv[c + 3], w[c + 3], s3);
    }
    s0 = fmaf(xv[16], w[16], s0);
    s1 = fmaf(xv[17], w[17], s1);
    s2 = fmaf(xv[18], w[18], s2);
    float s = (s0 + s1) + (s2 + s3);
    float pv = __expf(s);
    Z += pv;
#pragma unroll
    for (int c = 0; c < 19; ++c) outp[c] = fmaf(pv, u[c], outp[c]);
  }
#pragma unroll
  for (int c = 0; c < 19; ++c) red[kp][r][c] = outp[c];
  red[kp][r][19] = Z;
  __syncthreads();
  for (int idx = tid; idx < 64 * 19; idx += 1024) {
    int rr = idx / 19, d = idx % 19;
    float s = 0.f, Zs = 0.f;
#pragma unroll
    for (int q = 0; q < 16; ++q) { s += red[q][rr][d]; Zs += red[q][rr][19]; }
    cab[(size_t)blk * 64 * 19 + idx] = s / Zs;   // (blk*64+rr)*19+d
  }
}

// K4: out[hw+128 row][c] = relu(sum_d m2t[d][c]*cabD[d][hw]) + x[..][c]
// cabD[d][hw] = cab_flat[d*16384+hw] (reshape reinterpretation).
// Thread owns channel-quad c=4*tid (320 thr); 19 m2t coeffs float4 in regs;
// cab scalars via wave-uniform scalar loads; x/out as float4.
__global__ __launch_bounds__(320) void out_kernel(
    const float* __restrict__ x, const float* __restrict__ m2t,
    const float* __restrict__ cab, float* __restrict__ out)
{
  const int blk = blockIdx.x, tid = threadIdx.x;
  const int c4 = tid * 4;
  float4 mq[19];
#pragma unroll
  for (int d = 0; d < 19; ++d)
    mq[d] = *reinterpret_cast<const float4*>(m2t + d * 1280 + c4);
  const int hw0 = blk * 16;
#pragma unroll 4
  for (int p = 0; p < 16; ++p) {
    float4 a = make_float4(0.f, 0.f, 0.f, 0.f);
#pragma unroll
    for (int d = 0; d < 19; ++d) {
      const float f = cab[d * 16384 + hw0 + p];   // uniform -> s_load
      a.x = fmaf(mq[d].x, f, a.x);
      a.y = fmaf(mq[d].y, f, a.y);
      a.z = fmaf(mq[d].z, f, a.z);
      a.w = fmaf(mq[d].w, f, a.w);
    }
    const size_t addr = (size_t)(hw0 + p + 128) * 1280 + c4;
    const float4 xv4 = *reinterpret_cast<const float4*>(x + addr);
    float4 o4;
    o4.x = fmaxf(a.x, 0.f) + xv4.x;
    o4.y = fmaxf(a.y, 0.f) + xv4.y;
    o4.z = fmaxf(a.z, 0.f) + xv4.z;
    o4.w = fmaxf(a.w, 0.f) + xv4.w;
    *reinterpret_cast<float4*>(out + addr) = o4;
  }
}

extern "C" void kernel_launch(void* const* d_in, const int* in_sizes, int n_in,
                              void* d_out, int out_size, void* d_ws, size_t ws_size,
                              hipStream_t stream)
{
  const float* x     = (const float*)d_in[0];
  const float* v1    = (const float*)d_in[1];
  const float* v2    = (const float*)d_in[2];
  const float* w1    = (const float*)d_in[3];
  const float* w2    = (const float*)d_in[4];
  const float* intra = (const float*)d_in[5];
  const float* inter = (const float*)d_in[6];
  const int*   ip    = (const int*)d_in[7];
  float* out = (float*)d_out;
  float* ws  = (float*)d_ws;

  prep_kernel<<<912, 256, 0, stream>>>(v1, v2, w1, w2, intra, inter, ip, ws);
  xm_kernel<<<260, 1024, 0, stream>>>(x, ws /*m1*/, ws + OFF_XM, out);
  soft_kernel<<<256, 1024, 0, stream>>>(ws + OFF_XM, ws + OFF_IMT, ws + OFF_IM2, ws + OFF_CAB);
  out_kernel<<<1024, 320, 0, stream>>>(x, ws + OFF_M2T, ws + OFF_CAB, out);
}

// Round 3
// 135.382 us; speedup vs baseline: 1.3400x; 1.1943x over previous
//
#include <hip/hip_runtime.h>

// B=1, H=W=128, C=1280; HW=16384 pixels, 19 relation channels, 1024 keys.
//
// Algebra: x_m = (v2@v1)·x   (M1: 19x1280, stored transposed m1t[c][o])
//          cab = softmax(x_m·imt^T)·im2, im2 = imt@inter  (1024x19)
//          out = relu((w2@w1)·cab) + x  (M2 stored transposed m2t[d][o])
//
// ws layout (floats):
//   m1t : [1280][20] (pad)       off 0       len 25600   (M1^T: m1t[c][o])
//   m2t : [19][1280]             off 25600   len 24320   (m2t[d][o])
//   imt : [1024][20] (pad)       off 49920   len 20480   (intra[i]^T)
//   im2 : [1024][20] (pad)       off 70400   len 20480   (imt @ inter[i])
//   xm  : flat 19*16384          off 90880   len 311296  (o-major; reinterpreted n-major)
//   cab : flat 16384*19          off 402176  len 311296  (n-major; reinterpreted d-major)

#define OFF_M2T 25600
#define OFF_IMT 49920
#define OFF_IM2 70400
#define OFF_XM  90880
#define OFF_CAB 402176

__global__ __launch_bounds__(256) void prep_kernel(
    const float* __restrict__ v1, const float* __restrict__ v2,
    const float* __restrict__ w1, const float* __restrict__ w2,
    const float* __restrict__ intra, const float* __restrict__ inter,
    const int* __restrict__ ip, float* __restrict__ ws)
{
  float* m1t = ws;
  float* m2t = ws + OFF_M2T;
  float* imt = ws + OFF_IMT;
  float* im2 = ws + OFF_IM2;
  const int blk = blockIdx.x, tid = threadIdx.x;
  if (blk < 380) {
    // M1[o][j] = sum_c v2[o][c]*v1[c][j] -> stored m1t[j][o], 4-way c-split
    int g = blk * 256 + tid;
    int oidx = g >> 2, part = g & 3;
    int o = oidx / 1280, j = oidx - o * 1280;
    const float* v2r = v2 + o * 512 + part * 128;
    const float* v1c = v1 + part * 128 * 1280 + j;
    float acc = 0.f;
#pragma unroll 8
    for (int c = 0; c < 128; ++c) acc = fmaf(v2r[c], v1c[c * 1280], acc);
    acc += __shfl_xor(acc, 1);
    acc += __shfl_xor(acc, 2);
    if (part == 0) {
      m1t[j * 20 + o] = acc;
      if (o == 0) m1t[j * 20 + 19] = 0.f;
    }
  } else if (blk < 760) {
    // M2t[d][o] = sum_c w2[o][c]*w1[c][d]
    int g = (blk - 380) * 256 + tid;
    int oidx = g >> 2, part = g & 3;
    int o = oidx / 19, d = oidx - o * 19;
    const float* w2r = w2 + o * 512 + part * 128;
    const float* w1c = w1 + part * 128 * 19 + d;
    float acc = 0.f;
#pragma unroll 8
    for (int c = 0; c < 128; ++c) acc = fmaf(w2r[c], w1c[c * 19], acc);
    acc += __shfl_xor(acc, 1);
    acc += __shfl_xor(acc, 2);
    if (part == 0) m2t[d * 1280 + o] = acc;
  } else if (blk < 836) {
    // imt[k][c] = intra[i][c][k]
    int t = (blk - 760) * 256 + tid;
    int c = t >> 10, k = t & 1023;
    int iv = *ip;
    imt[k * 20 + c] = intra[(size_t)iv * 19456 + c * 1024 + k];
    if (c == 0) imt[k * 20 + 19] = 0.f;
  } else {
    // im2[k][d] = sum_c intra[i][c][k]*inter[i][c][d]
    int t = (blk - 836) * 256 + tid;
    int d = t >> 10, k = t & 1023;
    int iv = *ip;
    const float* ib = intra + (size_t)iv * 19456 + k;
    const float* ir = inter + (size_t)iv * 361 + d;
    float acc = 0.f;
#pragma unroll
    for (int c = 0; c < 19; ++c) acc = fmaf(ib[c * 1024], ir[c * 19], acc);
    im2[k * 20 + d] = acc;
    if (d == 0) im2[k * 20 + 19] = 0.f;
  }
}

// K2: xm[o][hw] = sum_c M1[o][c]*x[hw+128][c].
// Block = 64 pixels. 10 chunks of 128 c: coalesced float4 global loads ->
// LDS [px][128] with quad rotation g'=(g+px)&31 (b128 writes conflict-free);
// compute: lane=pixel, wave=c-slice (8 c), M1 coeffs via wave-uniform s_loads.
__global__ __launch_bounds__(1024) void xm_kernel(
    const float* __restrict__ x, const float* __restrict__ m1t,
    float* __restrict__ xm, float* __restrict__ out)
{
  __shared__ float sbuf[16 * 64 * 19];          // 76 KB; first 8192 aliased as x-stage
  float* xs = sbuf;
  const int blk = blockIdx.x, tid = threadIdx.x;
  if (blk < 256) {
    const int p  = tid & 63;
    const int kp = tid >> 6;
    const int kpu = __builtin_amdgcn_readfirstlane(kp);
    const int n0 = blk * 64;
    float acc[19];
#pragma unroll
    for (int o = 0; o < 19; ++o) acc[o] = 0.f;

    const int px0 = tid >> 5;                    // staging row (2 rows/wave)
    const int g0  = tid & 31;                    // staging quad
    for (int cc = 0; cc < 10; ++cc) {
#pragma unroll
      for (int i = 0; i < 2; ++i) {
        const int f = tid + i * 1024;
        const int px = f >> 5, g = f & 31;
        const float4 v = *reinterpret_cast<const float4*>(
            x + (size_t)(n0 + px + 128) * 1280 + cc * 128 + g * 4);
        const int gp = (g + px) & 31;
        *reinterpret_cast<float4*>(xs + px * 128 + gp * 4) = v;
      }
      __syncthreads();
      const float* wrow = m1t + (cc * 128 + kpu * 8) * 20;   // uniform
#pragma unroll
      for (int h = 0; h < 2; ++h) {
        const int g = kpu * 2 + h;
        const float4 xv = *reinterpret_cast<const float4*>(
            xs + p * 128 + (((g + p) & 31) << 2));
#pragma unroll
        for (int j = 0; j < 4; ++j) {
          const float* w = wrow + (h * 4 + j) * 20;          // uniform -> s_load
          const float xc = (&xv.x)[j];
#pragma unroll
          for (int o = 0; o < 19; ++o) acc[o] = fmaf(xc, w[o], acc[o]);
        }
      }
      __syncthreads();
    }
    // cross-wave reduce: red[kp][p][o], stride 19 (coprime 32 -> conflict-free)
#pragma unroll
    for (int o = 0; o < 19; ++o) sbuf[kp * 1216 + p * 19 + o] = acc[o];
    __syncthreads();
    for (int idx = tid; idx < 1216; idx += 1024) {
      const int o = idx >> 6, pp = idx & 63;
      float s = 0.f;
#pragma unroll
      for (int q = 0; q < 16; ++q) s += sbuf[q * 1216 + pp * 19 + o];
      xm[o * 16384 + n0 + pp] = s;
    }
  } else {
    // cls row copy: out[0][w][c] = x[0][w][c], 40960 float4
    const float4* xf = reinterpret_cast<const float4*>(x);
    float4* of = reinterpret_cast<float4*>(out);
    for (int idx = (blk - 256) * 1024 + tid; idx < 40960; idx += 8 * 1024)
      of[idx] = xf[idx];
  }
}

// K3: per row n: s_k = xv.imt[k]; p=exp(s); Z+=p; outd += p*im2[k];
// cab[n][d] = outd/Z. No max-subtraction: |s|=O(0.1), exp safe, partials add.
__global__ __launch_bounds__(1024) void soft_kernel(
    const float* __restrict__ xm, const float* __restrict__ imt,
    const float* __restrict__ im2, float* __restrict__ cab)
{
  __shared__ float red[16][64][20];
  const int blk = blockIdx.x, tid = threadIdx.x;
  const int r = tid & 63, kp = tid >> 6;
  const int kpu = __builtin_amdgcn_readfirstlane(kp);
  const int n = blk * 64 + r;

  const float* xrow = xm + (size_t)n * 19;
  float xv[19];
#pragma unroll
  for (int c = 0; c < 19; ++c) xv[c] = xrow[c];
  float outp[19];
#pragma unroll
  for (int c = 0; c < 19; ++c) outp[c] = 0.f;
  float Z = 0.f;
  const int kbase = kpu * 64;
  for (int k = kbase; k < kbase + 64; ++k) {
    const float* w = imt + k * 20;       // wave-uniform -> scalar loads
    const float* u = im2 + k * 20;
    float s0 = 0.f, s1 = 0.f, s2 = 0.f, s3 = 0.f;
#pragma unroll
    for (int c = 0; c < 16; c += 4) {
      s0 = fmaf(xv[c + 0], w[c + 0], s0);
      s1 = fmaf(xv[c + 1], w[c + 1], s1);
      s2 = fmaf(xv[c + 2], w[c + 2], s2);
      s3 = fmaf(xv[c + 3], w[c + 3], s3);
    }
    s0 = fmaf(xv[16], w[16], s0);
    s1 = fmaf(xv[17], w[17], s1);
    s2 = fmaf(xv[18], w[18], s2);
    float s = (s0 + s1) + (s2 + s3);
    float pv = __expf(s);
    Z += pv;
#pragma unroll
    for (int c = 0; c < 19; ++c) outp[c] = fmaf(pv, u[c], outp[c]);
  }
#pragma unroll
  for (int c = 0; c < 19; ++c) red[kp][r][c] = outp[c];
  red[kp][r][19] = Z;
  __syncthreads();
  for (int idx = tid; idx < 64 * 19; idx += 1024) {
    int rr = idx / 19, d = idx % 19;
    float s = 0.f, Zs = 0.f;
#pragma unroll
    for (int q = 0; q < 16; ++q) { s += red[q][rr][d]; Zs += red[q][rr][19]; }
    cab[(size_t)blk * 64 * 19 + idx] = s / Zs;   // (blk*64+rr)*19+d
  }
}

// K4: out[hw+128 row][c] = relu(sum_d m2t[d][c]*cabD[d][hw]) + x[..][c]
// cabD[d][hw] = cab_flat[d*16384+hw] (reshape reinterpretation).
__global__ __launch_bounds__(320) void out_kernel(
    const float* __restrict__ x, const float* __restrict__ m2t,
    const float* __restrict__ cab, float* __restrict__ out)
{
  const int blk = blockIdx.x, tid = threadIdx.x;
  const int c4 = tid * 4;
  float4 mq[19];
#pragma unroll
  for (int d = 0; d < 19; ++d)
    mq[d] = *reinterpret_cast<const float4*>(m2t + d * 1280 + c4);
  const int hw0 = blk * 16;
#pragma unroll 4
  for (int p = 0; p < 16; ++p) {
    float4 a = make_float4(0.f, 0.f, 0.f, 0.f);
#pragma unroll
    for (int d = 0; d < 19; ++d) {
      const float f = cab[d * 16384 + hw0 + p];   // uniform -> s_load
      a.x = fmaf(mq[d].x, f, a.x);
      a.y = fmaf(mq[d].y, f, a.y);
      a.z = fmaf(mq[d].z, f, a.z);
      a.w = fmaf(mq[d].w, f, a.w);
    }
    const size_t addr = (size_t)(hw0 + p + 128) * 1280 + c4;
    const float4 xv4 = *reinterpret_cast<const float4*>(x + addr);
    float4 o4;
    o4.x = fmaxf(a.x, 0.f) + xv4.x;
    o4.y = fmaxf(a.y, 0.f) + xv4.y;
    o4.z = fmaxf(a.z, 0.f) + xv4.z;
    o4.w = fmaxf(a.w, 0.f) + xv4.w;
    *reinterpret_cast<float4*>(out + addr) = o4;
  }
}

extern "C" void kernel_launch(void* const* d_in, const int* in_sizes, int n_in,
                              void* d_out, int out_size, void* d_ws, size_t ws_size,
                              hipStream_t stream)
{
  const float* x     = (const float*)d_in[0];
  const float* v1    = (const float*)d_in[1];
  const float* v2    = (const float*)d_in[2];
  const float* w1    = (const float*)d_in[3];
  const float* w2    = (const float*)d_in[4];
  const float* intra = (const float*)d_in[5];
  const float* inter = (const float*)d_in[6];
  const int*   ip    = (const int*)d_in[7];
  float* out = (float*)d_out;
  float* ws  = (float*)d_ws;

  prep_kernel<<<912, 256, 0, stream>>>(v1, v2, w1, w2, intra, inter, ip, ws);
  xm_kernel<<<264, 1024, 0, stream>>>(x, ws /*m1t*/, ws + OFF_XM, out);
  soft_kernel<<<256, 1024, 0, stream>>>(ws + OFF_XM, ws + OFF_IMT, ws + OFF_IM2, ws + OFF_CAB);
  out_kernel<<<1024, 320, 0, stream>>>(x, ws + OFF_M2T, ws + OFF_CAB, out);
}

// Round 4
// 113.796 us; speedup vs baseline: 1.5942x; 1.1897x over previous
//
#include <hip/hip_runtime.h>

// B=1, H=W=128, C=1280; HW=16384 pixels, 19 relation channels, 1024 keys.
//
// Algebra: x_m = (v2@v1)·x   (M1: 19x1280, stored transposed m1t[c][o])
//          cab = softmax(x_m·imt^T)·im2, im2 = imt@inter  (1024x19)
//          out = relu((w2@w1)·cab) + x  (M2 stored transposed m2t[d][o])
//
// ws layout (floats):
//   m1t : [1280][20] (pad)       off 0       len 25600   (M1^T: m1t[c][o])
//   m2t : [19][1280]             off 25600   len 24320   (m2t[d][o])
//   imt : [1024][20] (pad)       off 49920   len 20480   (intra[i]^T)
//   im2 : [1024][20] (pad)       off 70400   len 20480   (imt @ inter[i])
//   xm  : flat 19*16384          off 90880   len 311296  (o-major; reinterpreted n-major)
//   cab : flat 16384*19          off 402176  len 311296  (n-major; reinterpreted d-major)

#define OFF_M2T 25600
#define OFF_IMT 49920
#define OFF_IM2 70400
#define OFF_XM  90880
#define OFF_CAB 402176

typedef float vf4 __attribute__((ext_vector_type(4)));

__global__ __launch_bounds__(256) void prep_kernel(
    const float* __restrict__ v1, const float* __restrict__ v2,
    const float* __restrict__ w1, const float* __restrict__ w2,
    const float* __restrict__ intra, const float* __restrict__ inter,
    const int* __restrict__ ip, float* __restrict__ ws)
{
  float* m1t = ws;
  float* m2t = ws + OFF_M2T;
  float* imt = ws + OFF_IMT;
  float* im2 = ws + OFF_IM2;
  const int blk = blockIdx.x, tid = threadIdx.x;
  if (blk < 380) {
    // M1[o][j] = sum_c v2[o][c]*v1[c][j] -> stored m1t[j][o], 4-way c-split
    int g = blk * 256 + tid;
    int oidx = g >> 2, part = g & 3;
    int o = oidx / 1280, j = oidx - o * 1280;
    const float* v2r = v2 + o * 512 + part * 128;
    const float* v1c = v1 + part * 128 * 1280 + j;
    float acc = 0.f;
#pragma unroll 8
    for (int c = 0; c < 128; ++c) acc = fmaf(v2r[c], v1c[c * 1280], acc);
    acc += __shfl_xor(acc, 1);
    acc += __shfl_xor(acc, 2);
    if (part == 0) {
      m1t[j * 20 + o] = acc;
      if (o == 0) m1t[j * 20 + 19] = 0.f;
    }
  } else if (blk < 760) {
    // M2t[d][o] = sum_c w2[o][c]*w1[c][d]
    int g = (blk - 380) * 256 + tid;
    int oidx = g >> 2, part = g & 3;
    int o = oidx / 19, d = oidx - o * 19;
    const float* w2r = w2 + o * 512 + part * 128;
    const float* w1c = w1 + part * 128 * 19 + d;
    float acc = 0.f;
#pragma unroll 8
    for (int c = 0; c < 128; ++c) acc = fmaf(w2r[c], w1c[c * 19], acc);
    acc += __shfl_xor(acc, 1);
    acc += __shfl_xor(acc, 2);
    if (part == 0) m2t[d * 1280 + o] = acc;
  } else if (blk < 836) {
    // imt[k][c] = intra[i][c][k]
    int t = (blk - 760) * 256 + tid;
    int c = t >> 10, k = t & 1023;
    int iv = *ip;
    imt[k * 20 + c] = intra[(size_t)iv * 19456 + c * 1024 + k];
    if (c == 0) imt[k * 20 + 19] = 0.f;
  } else {
    // im2[k][d] = sum_c intra[i][c][k]*inter[i][c][d]
    int t = (blk - 836) * 256 + tid;
    int d = t >> 10, k = t & 1023;
    int iv = *ip;
    const float* ib = intra + (size_t)iv * 19456 + k;
    const float* ir = inter + (size_t)iv * 361 + d;
    float acc = 0.f;
#pragma unroll
    for (int c = 0; c < 19; ++c) acc = fmaf(ib[c * 1024], ir[c * 19], acc);
    im2[k * 20 + d] = acc;
    if (d == 0) im2[k * 20 + 19] = 0.f;
  }
}

// K2: xm[o][hw] = sum_c M1[o][c]*x[hw+128][c].
// Block = 64 pixels. 10 chunks of 128 c: coalesced float4 global loads ->
// LDS [px][128] with quad rotation g'=(g+px)&31 (b128 writes conflict-free);
// compute: lane=pixel, wave=c-slice (8 c), M1 coeffs via wave-uniform s_loads.
__global__ __launch_bounds__(1024) void xm_kernel(
    const float* __restrict__ x, const float* __restrict__ m1t,
    float* __restrict__ xm, float* __restrict__ out)
{
  __shared__ float sbuf[16 * 64 * 19];          // 76 KB; first 8192 aliased as x-stage
  float* xs = sbuf;
  const int blk = blockIdx.x, tid = threadIdx.x;
  if (blk < 256) {
    const int p  = tid & 63;
    const int kp = tid >> 6;
    const int kpu = __builtin_amdgcn_readfirstlane(kp);
    const int n0 = blk * 64;
    float acc[19];
#pragma unroll
    for (int o = 0; o < 19; ++o) acc[o] = 0.f;

    for (int cc = 0; cc < 10; ++cc) {
#pragma unroll
      for (int i = 0; i < 2; ++i) {
        const int f = tid + i * 1024;
        const int px = f >> 5, g = f & 31;
        const float4 v = *reinterpret_cast<const float4*>(
            x + (size_t)(n0 + px + 128) * 1280 + cc * 128 + g * 4);
        const int gp = (g + px) & 31;
        *reinterpret_cast<float4*>(xs + px * 128 + gp * 4) = v;
      }
      __syncthreads();
      const float* wrow = m1t + (cc * 128 + kpu * 8) * 20;   // uniform
#pragma unroll
      for (int h = 0; h < 2; ++h) {
        const int g = kpu * 2 + h;
        const float4 xv = *reinterpret_cast<const float4*>(
            xs + p * 128 + (((g + p) & 31) << 2));
#pragma unroll
        for (int j = 0; j < 4; ++j) {
          const float* w = wrow + (h * 4 + j) * 20;          // uniform -> s_load
          const float xc = (&xv.x)[j];
#pragma unroll
          for (int o = 0; o < 19; ++o) acc[o] = fmaf(xc, w[o], acc[o]);
        }
      }
      __syncthreads();
    }
    // cross-wave reduce: red[kp][p][o], stride 19 (coprime 32 -> conflict-free)
#pragma unroll
    for (int o = 0; o < 19; ++o) sbuf[kp * 1216 + p * 19 + o] = acc[o];
    __syncthreads();
    for (int idx = tid; idx < 1216; idx += 1024) {
      const int o = idx >> 6, pp = idx & 63;
      float s = 0.f;
#pragma unroll
      for (int q = 0; q < 16; ++q) s += sbuf[q * 1216 + pp * 19 + o];
      xm[o * 16384 + n0 + pp] = s;
    }
  } else {
    // cls row copy: out[0][w][c] = x[0][w][c], 40960 float4
    const float4* xf = reinterpret_cast<const float4*>(x);
    float4* of = reinterpret_cast<float4*>(out);
    for (int idx = (blk - 256) * 1024 + tid; idx < 40960; idx += 8 * 1024)
      of[idx] = xf[idx];
  }
}

// K3: per row n: s_k = xv.imt[k]; p=exp(s); Z+=p; outd += p*im2[k];
// cab[n][d] = outd/Z. No max-subtraction: |s|=O(0.1), exp safe, partials add.
__global__ __launch_bounds__(1024) void soft_kernel(
    const float* __restrict__ xm, const float* __restrict__ imt,
    const float* __restrict__ im2, float* __restrict__ cab)
{
  __shared__ float red[16][64][20];
  const int blk = blockIdx.x, tid = threadIdx.x;
  const int r = tid & 63, kp = tid >> 6;
  const int kpu = __builtin_amdgcn_readfirstlane(kp);
  const int n = blk * 64 + r;

  const float* xrow = xm + (size_t)n * 19;
  float xv[19];
#pragma unroll
  for (int c = 0; c < 19; ++c) xv[c] = xrow[c];
  float outp[19];
#pragma unroll
  for (int c = 0; c < 19; ++c) outp[c] = 0.f;
  float Z = 0.f;
  const int kbase = kpu * 64;
  for (int k = kbase; k < kbase + 64; ++k) {
    const float* w = imt + k * 20;       // wave-uniform -> scalar loads
    const float* u = im2 + k * 20;
    float s0 = 0.f, s1 = 0.f, s2 = 0.f, s3 = 0.f;
#pragma unroll
    for (int c = 0; c < 16; c += 4) {
      s0 = fmaf(xv[c + 0], w[c + 0], s0);
      s1 = fmaf(xv[c + 1], w[c + 1], s1);
      s2 = fmaf(xv[c + 2], w[c + 2], s2);
      s3 = fmaf(xv[c + 3], w[c + 3], s3);
    }
    s0 = fmaf(xv[16], w[16], s0);
    s1 = fmaf(xv[17], w[17], s1);
    s2 = fmaf(xv[18], w[18], s2);
    float s = (s0 + s1) + (s2 + s3);
    float pv = __expf(s);
    Z += pv;
#pragma unroll
    for (int c = 0; c < 19; ++c) outp[c] = fmaf(pv, u[c], outp[c]);
  }
#pragma unroll
  for (int c = 0; c < 19; ++c) red[kp][r][c] = outp[c];
  red[kp][r][19] = Z;
  __syncthreads();
  for (int idx = tid; idx < 64 * 19; idx += 1024) {
    int rr = idx / 19, d = idx % 19;
    float s = 0.f, Zs = 0.f;
#pragma unroll
    for (int q = 0; q < 16; ++q) { s += red[q][rr][d]; Zs += red[q][rr][19]; }
    cab[(size_t)blk * 64 * 19 + idx] = s / Zs;   // (blk*64+rr)*19+d
  }
}

// K4: out[hw+128 row][c] = relu(sum_d m2t[d][c]*cabD[d][hw]) + x[..][c]
// cabD[d][hw] = cab_flat[d*16384+hw] (reshape reinterpretation).
// 2048 blocks x 8 px; thread owns channel-quad c4=tid*4; 19 m2t coeffs in
// regs; cab via wave-uniform s_loads; x float4 preloaded 4-deep; nt stores
// (out never re-read -> keep x resident in L3 across replays).
__global__ __launch_bounds__(320, 4) void out_kernel(
    const float* __restrict__ x, const float* __restrict__ m2t,
    const float* __restrict__ cab, float* __restrict__ out)
{
  const int blk = blockIdx.x, tid = threadIdx.x;
  const int c4 = tid * 4;
  float4 mq[19];
#pragma unroll
  for (int d = 0; d < 19; ++d)
    mq[d] = *reinterpret_cast<const float4*>(m2t + d * 1280 + c4);
  const int hw0 = blk * 8;
#pragma unroll
  for (int grp = 0; grp < 2; ++grp) {
    const int p0 = grp * 4;
    // issue all 4 x-loads before any dependent compute
    float4 xv[4];
#pragma unroll
    for (int q = 0; q < 4; ++q)
      xv[q] = *reinterpret_cast<const float4*>(
          x + (size_t)(hw0 + p0 + q + 128) * 1280 + c4);
#pragma unroll
    for (int q = 0; q < 4; ++q) {
      const int p = p0 + q;
      float4 a = make_float4(0.f, 0.f, 0.f, 0.f);
#pragma unroll
      for (int d = 0; d < 19; ++d) {
        const float f = cab[d * 16384 + hw0 + p];   // uniform -> s_load
        a.x = fmaf(mq[d].x, f, a.x);
        a.y = fmaf(mq[d].y, f, a.y);
        a.z = fmaf(mq[d].z, f, a.z);
        a.w = fmaf(mq[d].w, f, a.w);
      }
      vf4 o4;
      o4.x = fmaxf(a.x, 0.f) + xv[q].x;
      o4.y = fmaxf(a.y, 0.f) + xv[q].y;
      o4.z = fmaxf(a.z, 0.f) + xv[q].z;
      o4.w = fmaxf(a.w, 0.f) + xv[q].w;
      const size_t addr = (size_t)(hw0 + p + 128) * 1280 + c4;
      __builtin_nontemporal_store(o4, reinterpret_cast<vf4*>(out + addr));
    }
  }
}

extern "C" void kernel_launch(void* const* d_in, const int* in_sizes, int n_in,
                              void* d_out, int out_size, void* d_ws, size_t ws_size,
                              hipStream_t stream)
{
  const float* x     = (const float*)d_in[0];
  const float* v1    = (const float*)d_in[1];
  const float* v2    = (const float*)d_in[2];
  const float* w1    = (const float*)d_in[3];
  const float* w2    = (const float*)d_in[4];
  const float* intra = (const float*)d_in[5];
  const float* inter = (const float*)d_in[6];
  const int*   ip    = (const int*)d_in[7];
  float* out = (float*)d_out;
  float* ws  = (float*)d_ws;

  prep_kernel<<<912, 256, 0, stream>>>(v1, v2, w1, w2, intra, inter, ip, ws);
  xm_kernel<<<264, 1024, 0, stream>>>(x, ws /*m1t*/, ws + OFF_XM, out);
  soft_kernel<<<256, 1024, 0, stream>>>(ws + OFF_XM, ws + OFF_IMT, ws + OFF_IM2, ws + OFF_CAB);
  out_kernel<<<2048, 320, 0, stream>>>(x, ws + OFF_M2T, ws + OFF_CAB, out);
}

// Round 5
// 104.847 us; speedup vs baseline: 1.7303x; 1.0854x over previous
//
#include <hip/hip_runtime.h>

// B=1, H=W=128, C=1280; HW=16384 pixels, 19 relation channels, 1024 keys.
//
// Algebra: x_m = (v2@v1)·x   (M1: 19x1280, stored transposed m1t[c][o])
//          cab = softmax(x_m·imt^T)·im2, im2 = imt@inter  (1024x19)
//          out = relu((w2@w1)·cab) + x  (M2 stored transposed m2t[d][o])
//
// ws layout (floats):
//   m1t : [1280][20] (pad)       off 0       len 25600   (M1^T: m1t[c][o])
//   m2t : [19][1280]             off 25600   len 24320   (m2t[d][o])
//   imt : [1024][20] (pad)       off 49920   len 20480   (intra[i]^T)
//   im2 : [1024][20] (pad)       off 70400   len 20480   (imt @ inter[i])
//   xm  : flat 19*16384          off 90880   len 311296  (o-major; reinterpreted n-major)
//   cab : flat 16384*19          off 402176  len 311296  (n-major; reinterpreted d-major)

#define OFF_M2T 25600
#define OFF_IMT 49920
#define OFF_IM2 70400
#define OFF_XM  90880
#define OFF_CAB 402176

typedef float vf4 __attribute__((ext_vector_type(4)));

__global__ __launch_bounds__(256) void prep_kernel(
    const float* __restrict__ v1, const float* __restrict__ v2,
    const float* __restrict__ w1, const float* __restrict__ w2,
    const float* __restrict__ intra, const float* __restrict__ inter,
    const int* __restrict__ ip, float* __restrict__ ws)
{
  float* m1t = ws;
  float* m2t = ws + OFF_M2T;
  float* imt = ws + OFF_IMT;
  float* im2 = ws + OFF_IM2;
  const int blk = blockIdx.x, tid = threadIdx.x;
  if (blk < 380) {
    // M1[o][j] = sum_c v2[o][c]*v1[c][j] -> stored m1t[j][o], 4-way c-split
    int g = blk * 256 + tid;
    int oidx = g >> 2, part = g & 3;
    int o = oidx / 1280, j = oidx - o * 1280;
    const float* v2r = v2 + o * 512 + part * 128;
    const float* v1c = v1 + part * 128 * 1280 + j;
    float acc = 0.f;
#pragma unroll 8
    for (int c = 0; c < 128; ++c) acc = fmaf(v2r[c], v1c[c * 1280], acc);
    acc += __shfl_xor(acc, 1);
    acc += __shfl_xor(acc, 2);
    if (part == 0) {
      m1t[j * 20 + o] = acc;
      if (o == 0) m1t[j * 20 + 19] = 0.f;
    }
  } else if (blk < 760) {
    // M2t[d][o] = sum_c w2[o][c]*w1[c][d]
    int g = (blk - 380) * 256 + tid;
    int oidx = g >> 2, part = g & 3;
    int o = oidx / 19, d = oidx - o * 19;
    const float* w2r = w2 + o * 512 + part * 128;
    const float* w1c = w1 + part * 128 * 19 + d;
    float acc = 0.f;
#pragma unroll 8
    for (int c = 0; c < 128; ++c) acc = fmaf(w2r[c], w1c[c * 19], acc);
    acc += __shfl_xor(acc, 1);
    acc += __shfl_xor(acc, 2);
    if (part == 0) m2t[d * 1280 + o] = acc;
  } else if (blk < 836) {
    // imt[k][c] = intra[i][c][k]
    int t = (blk - 760) * 256 + tid;
    int c = t >> 10, k = t & 1023;
    int iv = *ip;
    imt[k * 20 + c] = intra[(size_t)iv * 19456 + c * 1024 + k];
    if (c == 0) imt[k * 20 + 19] = 0.f;
  } else {
    // im2[k][d] = sum_c intra[i][c][k]*inter[i][c][d]
    int t = (blk - 836) * 256 + tid;
    int d = t >> 10, k = t & 1023;
    int iv = *ip;
    const float* ib = intra + (size_t)iv * 19456 + k;
    const float* ir = inter + (size_t)iv * 361 + d;
    float acc = 0.f;
#pragma unroll
    for (int c = 0; c < 19; ++c) acc = fmaf(ib[c * 1024], ir[c * 19], acc);
    im2[k * 20 + d] = acc;
    if (d == 0) im2[k * 20 + 19] = 0.f;
  }
}

#define XM_FMA19(XC, W)                                                  \
  a00 = fmaf((XC), (W)[0],  a00); a01 = fmaf((XC), (W)[1],  a01);        \
  a02 = fmaf((XC), (W)[2],  a02); a03 = fmaf((XC), (W)[3],  a03);        \
  a04 = fmaf((XC), (W)[4],  a04); a05 = fmaf((XC), (W)[5],  a05);        \
  a06 = fmaf((XC), (W)[6],  a06); a07 = fmaf((XC), (W)[7],  a07);        \
  a08 = fmaf((XC), (W)[8],  a08); a09 = fmaf((XC), (W)[9],  a09);        \
  a10 = fmaf((XC), (W)[10], a10); a11 = fmaf((XC), (W)[11], a11);        \
  a12 = fmaf((XC), (W)[12], a12); a13 = fmaf((XC), (W)[13], a13);        \
  a14 = fmaf((XC), (W)[14], a14); a15 = fmaf((XC), (W)[15], a15);        \
  a16 = fmaf((XC), (W)[16], a16); a17 = fmaf((XC), (W)[17], a17);        \
  a18 = fmaf((XC), (W)[18], a18);

// K2: xm[o][hw] = sum_c M1[o][c]*x[hw+128][c].
// Block = 64 px. 10 chunks of 128 c. Reg-staged double-buffered LDS transpose:
// issue chunk c+1 global loads (coalesced float4) before computing chunk c
// from LDS (quad-rotation swizzle, conflict-free); ONE barrier per chunk.
// Named scalar accumulators (a00..a18) -> guaranteed registers, no scratch.
__global__ __launch_bounds__(1024) void xm_kernel(
    const float* __restrict__ x, const float* __restrict__ m1t,
    float* __restrict__ xm, float* __restrict__ out)
{
  __shared__ float sbuf[19456];                 // 76 KB: 2x8192 stage, then reduce
  const int blk = blockIdx.x, tid = threadIdx.x;
  if (blk < 256) {
    const int p  = tid & 63;
    const int kp = tid >> 6;
    const int kpu = __builtin_amdgcn_readfirstlane(kp);
    const int n0 = blk * 64;
    const float* xg = x + (size_t)(n0 + 128) * 1280;

    // staging geometry (two float4 per thread per chunk)
    const int px0 = tid >> 5, g0 = tid & 31;
    const int px1 = px0 + 32;
    const size_t ga0 = (size_t)px0 * 1280 + g0 * 4;
    const size_t ga1 = (size_t)px1 * 1280 + g0 * 4;
    const int st0 = px0 * 128 + (((g0 + px0) & 31) << 2);
    const int st1 = px1 * 128 + (((g0 + px1) & 31) << 2);
    // compute-side LDS read offsets (logical quads kpu*2, kpu*2+1 rotated by p)
    const int rd0 = p * 128 + ((((kpu * 2 + 0) + p) & 31) << 2);
    const int rd1 = p * 128 + ((((kpu * 2 + 1) + p) & 31) << 2);

    float a00 = 0.f, a01 = 0.f, a02 = 0.f, a03 = 0.f, a04 = 0.f;
    float a05 = 0.f, a06 = 0.f, a07 = 0.f, a08 = 0.f, a09 = 0.f;
    float a10 = 0.f, a11 = 0.f, a12 = 0.f, a13 = 0.f, a14 = 0.f;
    float a15 = 0.f, a16 = 0.f, a17 = 0.f, a18 = 0.f;

    // prologue: stage chunk 0 into buffer 0
    {
      const float4 r0 = *reinterpret_cast<const float4*>(xg + ga0);
      const float4 r1 = *reinterpret_cast<const float4*>(xg + ga1);
      *reinterpret_cast<float4*>(sbuf + st0) = r0;
      *reinterpret_cast<float4*>(sbuf + st1) = r1;
    }
    __syncthreads();

    for (int cc = 0; cc < 10; ++cc) {
      float4 n0v, n1v;
      if (cc < 9) {                    // issue next-chunk loads early (T14)
        n0v = *reinterpret_cast<const float4*>(xg + ga0 + (cc + 1) * 128);
        n1v = *reinterpret_cast<const float4*>(xg + ga1 + (cc + 1) * 128);
      }
      const float* buf = sbuf + (cc & 1) * 8192;
      const float4 xv0 = *reinterpret_cast<const float4*>(buf + rd0);
      const float4 xv1 = *reinterpret_cast<const float4*>(buf + rd1);
      const float* wrow = m1t + (cc * 128 + kpu * 8) * 20;   // uniform -> s_load
      XM_FMA19(xv0.x, wrow);
      XM_FMA19(xv0.y, wrow + 20);
      XM_FMA19(xv0.z, wrow + 40);
      XM_FMA19(xv0.w, wrow + 60);
      XM_FMA19(xv1.x, wrow + 80);
      XM_FMA19(xv1.y, wrow + 100);
      XM_FMA19(xv1.z, wrow + 120);
      XM_FMA19(xv1.w, wrow + 140);
      if (cc < 9) {
        float* nbuf = sbuf + ((cc + 1) & 1) * 8192;
        *reinterpret_cast<float4*>(nbuf + st0) = n0v;
        *reinterpret_cast<float4*>(nbuf + st1) = n1v;
      }
      __syncthreads();
    }

    // cross-wave reduce: stride 19 (coprime 32 -> conflict-free)
    {
      float* rb = sbuf + kp * 1216 + p * 19;
      rb[0] = a00;  rb[1] = a01;  rb[2] = a02;  rb[3] = a03;  rb[4] = a04;
      rb[5] = a05;  rb[6] = a06;  rb[7] = a07;  rb[8] = a08;  rb[9] = a09;
      rb[10] = a10; rb[11] = a11; rb[12] = a12; rb[13] = a13; rb[14] = a14;
      rb[15] = a15; rb[16] = a16; rb[17] = a17; rb[18] = a18;
    }
    __syncthreads();
    for (int idx = tid; idx < 1216; idx += 1024) {
      const int o = idx >> 6, pp = idx & 63;
      float s = 0.f;
#pragma unroll
      for (int q = 0; q < 16; ++q) s += sbuf[q * 1216 + pp * 19 + o];
      xm[o * 16384 + n0 + pp] = s;
    }
  } else {
    // cls row copy: out[0][w][c] = x[0][w][c], 40960 float4
    const float4* xf = reinterpret_cast<const float4*>(x);
    float4* of = reinterpret_cast<float4*>(out);
    for (int idx = (blk - 256) * 1024 + tid; idx < 40960; idx += 8 * 1024)
      of[idx] = xf[idx];
  }
}

#define SOFT_ACC19(PV, U)                                                \
  o00 = fmaf((PV), (U)[0],  o00); o01 = fmaf((PV), (U)[1],  o01);        \
  o02 = fmaf((PV), (U)[2],  o02); o03 = fmaf((PV), (U)[3],  o03);        \
  o04 = fmaf((PV), (U)[4],  o04); o05 = fmaf((PV), (U)[5],  o05);        \
  o06 = fmaf((PV), (U)[6],  o06); o07 = fmaf((PV), (U)[7],  o07);        \
  o08 = fmaf((PV), (U)[8],  o08); o09 = fmaf((PV), (U)[9],  o09);        \
  o10 = fmaf((PV), (U)[10], o10); o11 = fmaf((PV), (U)[11], o11);        \
  o12 = fmaf((PV), (U)[12], o12); o13 = fmaf((PV), (U)[13], o13);        \
  o14 = fmaf((PV), (U)[14], o14); o15 = fmaf((PV), (U)[15], o15);        \
  o16 = fmaf((PV), (U)[16], o16); o17 = fmaf((PV), (U)[17], o17);        \
  o18 = fmaf((PV), (U)[18], o18);

// K3: per row n: s_k = xv.imt[k]; p=exp(s); Z+=p; outd += p*im2[k];
// cab[n][d] = outd/Z. No max-subtraction: |s|=O(0.1), exp safe, partials add.
// Named scalars throughout; xm rows staged via LDS (coalesced).
__global__ __launch_bounds__(1024) void soft_kernel(
    const float* __restrict__ xm, const float* __restrict__ imt,
    const float* __restrict__ im2, float* __restrict__ cab)
{
  __shared__ float red[16][64][20];
  __shared__ float xstage[1216];
  const int blk = blockIdx.x, tid = threadIdx.x;
  const int r = tid & 63, kp = tid >> 6;
  const int kpu = __builtin_amdgcn_readfirstlane(kp);
  const int n0 = blk * 64;

  // coalesced stage of the 64 xm rows (flat [n][19] reinterpretation)
  for (int idx = tid; idx < 1216; idx += 1024)
    xstage[idx] = xm[(size_t)n0 * 19 + idx];
  __syncthreads();

  const float* xr = xstage + r * 19;
  const float x00 = xr[0],  x01 = xr[1],  x02 = xr[2],  x03 = xr[3];
  const float x04 = xr[4],  x05 = xr[5],  x06 = xr[6],  x07 = xr[7];
  const float x08 = xr[8],  x09 = xr[9],  x10 = xr[10], x11 = xr[11];
  const float x12 = xr[12], x13 = xr[13], x14 = xr[14], x15 = xr[15];
  const float x16 = xr[16], x17 = xr[17], x18 = xr[18];

  float o00 = 0.f, o01 = 0.f, o02 = 0.f, o03 = 0.f, o04 = 0.f;
  float o05 = 0.f, o06 = 0.f, o07 = 0.f, o08 = 0.f, o09 = 0.f;
  float o10 = 0.f, o11 = 0.f, o12 = 0.f, o13 = 0.f, o14 = 0.f;
  float o15 = 0.f, o16 = 0.f, o17 = 0.f, o18 = 0.f;
  float Z = 0.f;
  const int kbase = kpu * 64;
  for (int k = kbase; k < kbase + 64; ++k) {
    const float* w = imt + k * 20;       // wave-uniform -> scalar loads
    const float* u = im2 + k * 20;
    float s0 = x00 * w[0];
    s0 = fmaf(x04, w[4], s0); s0 = fmaf(x08, w[8],  s0);
    s0 = fmaf(x12, w[12], s0); s0 = fmaf(x16, w[16], s0);
    float s1 = x01 * w[1];
    s1 = fmaf(x05, w[5], s1); s1 = fmaf(x09, w[9],  s1);
    s1 = fmaf(x13, w[13], s1); s1 = fmaf(x17, w[17], s1);
    float s2 = x02 * w[2];
    s2 = fmaf(x06, w[6], s2); s2 = fmaf(x10, w[10], s2);
    s2 = fmaf(x14, w[14], s2); s2 = fmaf(x18, w[18], s2);
    float s3 = x03 * w[3];
    s3 = fmaf(x07, w[7], s3); s3 = fmaf(x11, w[11], s3);
    s3 = fmaf(x15, w[15], s3);
    const float s = (s0 + s1) + (s2 + s3);
    const float pv = __expf(s);
    Z += pv;
    SOFT_ACC19(pv, u);
  }
  {
    float* rb = &red[kp][r][0];
    rb[0] = o00;  rb[1] = o01;  rb[2] = o02;  rb[3] = o03;  rb[4] = o04;
    rb[5] = o05;  rb[6] = o06;  rb[7] = o07;  rb[8] = o08;  rb[9] = o09;
    rb[10] = o10; rb[11] = o11; rb[12] = o12; rb[13] = o13; rb[14] = o14;
    rb[15] = o15; rb[16] = o16; rb[17] = o17; rb[18] = o18; rb[19] = Z;
  }
  __syncthreads();
  for (int idx = tid; idx < 64 * 19; idx += 1024) {
    int rr = idx / 19, d = idx % 19;
    float s = 0.f, Zs = 0.f;
#pragma unroll
    for (int q = 0; q < 16; ++q) { s += red[q][rr][d]; Zs += red[q][rr][19]; }
    cab[(size_t)blk * 64 * 19 + idx] = s / Zs;   // (blk*64+rr)*19+d
  }
}

// K4: out[hw+128 row][c] = relu(sum_d m2t[d][c]*cabD[d][hw]) + x[..][c]
// cabD[d][hw] = cab_flat[d*16384+hw] (reshape reinterpretation).
// 2048 blocks x 8 px; thread owns channel-quad c4=tid*4; 19 m2t coeffs in
// regs; cab via wave-uniform s_loads; x float4 preloaded 4-deep; nt stores.
__global__ __launch_bounds__(320, 4) void out_kernel(
    const float* __restrict__ x, const float* __restrict__ m2t,
    const float* __restrict__ cab, float* __restrict__ out)
{
  const int blk = blockIdx.x, tid = threadIdx.x;
  const int c4 = tid * 4;
  float4 mq[19];
#pragma unroll
  for (int d = 0; d < 19; ++d)
    mq[d] = *reinterpret_cast<const float4*>(m2t + d * 1280 + c4);
  const int hw0 = blk * 8;
#pragma unroll
  for (int grp = 0; grp < 2; ++grp) {
    const int p0 = grp * 4;
    float4 xv[4];
#pragma unroll
    for (int q = 0; q < 4; ++q)
      xv[q] = *reinterpret_cast<const float4*>(
          x + (size_t)(hw0 + p0 + q + 128) * 1280 + c4);
#pragma unroll
    for (int q = 0; q < 4; ++q) {
      const int p = p0 + q;
      float4 a = make_float4(0.f, 0.f, 0.f, 0.f);
#pragma unroll
      for (int d = 0; d < 19; ++d) {
        const float f = cab[d * 16384 + hw0 + p];   // uniform -> s_load
        a.x = fmaf(mq[d].x, f, a.x);
        a.y = fmaf(mq[d].y, f, a.y);
        a.z = fmaf(mq[d].z, f, a.z);
        a.w = fmaf(mq[d].w, f, a.w);
      }
      vf4 o4;
      o4.x = fmaxf(a.x, 0.f) + xv[q].x;
      o4.y = fmaxf(a.y, 0.f) + xv[q].y;
      o4.z = fmaxf(a.z, 0.f) + xv[q].z;
      o4.w = fmaxf(a.w, 0.f) + xv[q].w;
      const size_t addr = (size_t)(hw0 + p + 128) * 1280 + c4;
      __builtin_nontemporal_store(o4, reinterpret_cast<vf4*>(out + addr));
    }
  }
}

extern "C" void kernel_launch(void* const* d_in, const int* in_sizes, int n_in,
                              void* d_out, int out_size, void* d_ws, size_t ws_size,
                              hipStream_t stream)
{
  const float* x     = (const float*)d_in[0];
  const float* v1    = (const float*)d_in[1];
  const float* v2    = (const float*)d_in[2];
  const float* w1    = (const float*)d_in[3];
  const float* w2    = (const float*)d_in[4];
  const float* intra = (const float*)d_in[5];
  const float* inter = (const float*)d_in[6];
  const int*   ip    = (const int*)d_in[7];
  float* out = (float*)d_out;
  float* ws  = (float*)d_ws;

  prep_kernel<<<912, 256, 0, stream>>>(v1, v2, w1, w2, intra, inter, ip, ws);
  xm_kernel<<<264, 1024, 0, stream>>>(x, ws /*m1t*/, ws + OFF_XM, out);
  soft_kernel<<<256, 1024, 0, stream>>>(ws + OFF_XM, ws + OFF_IMT, ws + OFF_IM2, ws + OFF_CAB);
  out_kernel<<<2048, 320, 0, stream>>>(x, ws + OFF_M2T, ws + OFF_CAB, out);
}